// Round 1
// baseline (416.277 us; speedup 1.0000x reference)
//
#include <hip/hip_runtime.h>
#include <hip/hip_bf16.h>

// MHA: B=4, S=2048, D_MODEL=1024, H=16, DK=64
// ws layout (bytes):
//   [0, 8388608)            Wt: 4 x bf16[1024][1024]  (row n, col k)  = W^T
//   [8388608, +16777216)    Q  bf16 [B][H][S][64]
//   next  +16777216         K  bf16 [B][H][S][64]
//   next  +16777216         V  bf16 [B][H][64][S]
//   next  +16777216         attn out bf16 [8192][1024]
//   next  +2097152          mask bits u64 [B][S][S/64]
// total 77,594,624 B

typedef __bf16 bf16;
typedef __bf16 bf16x4 __attribute__((ext_vector_type(4)));
typedef __bf16 bf16x8 __attribute__((ext_vector_type(8)));
typedef float f32x4 __attribute__((ext_vector_type(4)));

__device__ __forceinline__ void gload_lds16(const void* g, void* l) {
  __builtin_amdgcn_global_load_lds(
      (__attribute__((address_space(1))) void*)g,
      (__attribute__((address_space(3))) void*)l, 16, 0, 0);
}

// ---------------- W transpose + bf16 convert ----------------
__global__ __launch_bounds__(256) void wt_kernel(const float* __restrict__ Wq,
                                                 const float* __restrict__ Wk,
                                                 const float* __restrict__ Wv,
                                                 const float* __restrict__ Wo,
                                                 bf16* __restrict__ wt) {
  __shared__ float tile[64][65];
  const int z = blockIdx.z;
  const float* W = (z == 0) ? Wq : (z == 1) ? Wk : (z == 2) ? Wv : Wo;
  bf16* out = wt + (size_t)z * 1048576;
  const int k0 = blockIdx.x * 64, n0 = blockIdx.y * 64;
  for (int e = threadIdx.x; e < 4096; e += 256) {
    int r = e >> 6, c = e & 63;
    tile[r][c] = W[(size_t)(k0 + r) * 1024 + n0 + c];
  }
  __syncthreads();
  for (int e = threadIdx.x; e < 4096; e += 256) {
    int r = e >> 6, c = e & 63;
    out[(size_t)(n0 + r) * 1024 + k0 + c] = (bf16)tile[c][r];
  }
}

// ---------------- mask -> bit pack ----------------
__global__ __launch_bounds__(256) void maskpack_kernel(const int* __restrict__ mask,
                                                       unsigned long long* __restrict__ bits) {
  const int gid = blockIdx.x * 256 + threadIdx.x;
  const int word = gid >> 6;
  const int lane = threadIdx.x & 63;
  int v = mask[(size_t)word * 64 + lane];
  unsigned long long b = __ballot(v != 0);
  if (lane == 0) bits[word] = b;
}

// ---------------- GEMM: C[8192][1024] = A[8192][1024] @ Bt^T + bias ----------------
// MODE 0: A fp32, out Q bf16 [B][H][S][64], (acc+bias)*0.125
// MODE 1: A fp32, out K bf16 [B][H][S][64]
// MODE 2: A fp32, out V bf16 [B][H][64][S]
// MODE 3: A bf16, out fp32 row-major [8192][1024]
template <int MODE>
__global__ __launch_bounds__(256) void gemm_kernel(const void* __restrict__ Aptr,
                                                   const bf16* __restrict__ Bt,
                                                   const float* __restrict__ bias,
                                                   void* __restrict__ Out) {
  __shared__ alignas(16) char smem[32768];
  char* As = smem;            // [128][64] bf16, 16B-slot XOR swizzle by row&7
  char* Bs = smem + 16384;    // [128 n][64 k] bf16, same swizzle
  const int t = threadIdx.x;
  const int w = t >> 6, l = t & 63;
  const int hi = l >> 4, lo = l & 15, l7 = l & 7;
  const int wr = w >> 1, wc = w & 1;
  const int row0 = blockIdx.x * 128;
  const int n0 = blockIdx.y * 128;

  const f32x4 fz = {0.f, 0.f, 0.f, 0.f};
  f32x4 acc[4][4];
#pragma unroll
  for (int mi = 0; mi < 4; ++mi)
#pragma unroll
    for (int ni = 0; ni < 4; ++ni) acc[mi][ni] = fz;

  for (int kt = 0; kt < 16; ++kt) {
    if constexpr (MODE < 3) {
      const float* A = (const float*)Aptr;
#pragma unroll
      for (int i = 0; i < 8; ++i) {
        int qq = i * 256 + t;
        int r = qq >> 4, q = qq & 15;  // row, 4-float quad along k
        f32x4 f = *(const f32x4*)(A + (size_t)(row0 + r) * 1024 + kt * 64 + q * 4);
        bf16x4 h = {(bf16)f[0], (bf16)f[1], (bf16)f[2], (bf16)f[3]};
        *(bf16x4*)(As + r * 128 + ((q * 8) ^ ((r & 7) << 4))) = h;
      }
    } else {
      const char* A = (const char*)Aptr;  // bf16 [8192][1024]
#pragma unroll
      for (int i = 0; i < 4; ++i) {
        int c = i * 256 + t;
        int r = c >> 3, s = c & 7;
        gload_lds16(A + (size_t)(row0 + r) * 2048 + kt * 128 + ((s ^ (r & 7)) * 16),
                    As + (i * 256 + w * 64) * 16);
      }
    }
    {
      const char* Bb = (const char*)Bt;  // bf16 [1024 n][1024 k]
#pragma unroll
      for (int i = 0; i < 4; ++i) {
        int c = i * 256 + t;
        int r = c >> 3, s = c & 7;
        gload_lds16(Bb + (size_t)(n0 + r) * 2048 + kt * 128 + ((s ^ (r & 7)) * 16),
                    Bs + (i * 256 + w * 64) * 16);
      }
    }
    __syncthreads();
#pragma unroll
    for (int kk = 0; kk < 2; ++kk) {
      bf16x8 af[4], bfr[4];
#pragma unroll
      for (int mi = 0; mi < 4; ++mi)
        af[mi] = *(const bf16x8*)(As + (wr * 64 + mi * 16 + lo) * 128 +
                                  ((kk * 64 + hi * 16) ^ (l7 << 4)));
#pragma unroll
      for (int ni = 0; ni < 4; ++ni)
        bfr[ni] = *(const bf16x8*)(Bs + (wc * 64 + ni * 16 + lo) * 128 +
                                   ((kk * 64 + hi * 16) ^ (l7 << 4)));
#pragma unroll
      for (int mi = 0; mi < 4; ++mi)
#pragma unroll
        for (int ni = 0; ni < 4; ++ni)
          acc[mi][ni] =
              __builtin_amdgcn_mfma_f32_16x16x32_bf16(af[mi], bfr[ni], acc[mi][ni], 0, 0, 0);
    }
    __syncthreads();
  }

  // epilogue: D row=(lane>>4)*4+j, col=lane&15 (m89-verified)
#pragma unroll
  for (int mi = 0; mi < 4; ++mi)
#pragma unroll
    for (int ni = 0; ni < 4; ++ni) {
      int gcol = n0 + wc * 64 + ni * 16 + lo;
      float bv = bias[gcol];
#pragma unroll
      for (int j = 0; j < 4; ++j) {
        int grow = row0 + wr * 64 + mi * 16 + hi * 4 + j;
        float v = acc[mi][ni][j] + bv;
        if constexpr (MODE == 0) v *= 0.125f;  // fold 1/sqrt(DK) into Q
        if constexpr (MODE <= 1) {
          int b = grow >> 11, si = grow & 2047, h = gcol >> 6, d = gcol & 63;
          ((bf16*)Out)[((((size_t)b * 16 + h) * 2048 + si) << 6) + d] = (bf16)v;
        } else if constexpr (MODE == 2) {
          int b = grow >> 11, si = grow & 2047, h = gcol >> 6, d = gcol & 63;
          ((bf16*)Out)[((((size_t)b * 16 + h) * 64 + d) << 11) + si] = (bf16)v;
        } else {
          ((float*)Out)[(size_t)grow * 1024 + gcol] = v;
        }
      }
    }
}

// ---------------- flash attention ----------------
// grid (S/128, B*H), 256 thr. wave w owns q rows [q0+32w, q0+32w+32)
__global__ __launch_bounds__(256) void attn_kernel(const char* __restrict__ qb,
                                                   const char* __restrict__ kb,
                                                   const char* __restrict__ vb,
                                                   const unsigned long long* __restrict__ mbits,
                                                   bf16* __restrict__ out) {
  __shared__ alignas(16) char smem[32768];
  char* Ks = smem;           // [64 kj][64 d] bf16, swizzled
  char* Vs = smem + 8192;    // [64 d][64 kj] bf16, swizzled
  const int t = threadIdx.x;
  const int w = t >> 6, l = t & 63;
  const int hi = l >> 4, lo = l & 15, l7 = l & 7;
  char* Ps = smem + 16384 + w * 4096;  // per-wave P [32][64] bf16, swizzled
  const int bh = blockIdx.y, b = bh >> 4;
  const int q0 = blockIdx.x * 128;

  // Q fragments in registers (already scaled by 0.125 at projection)
  bf16x8 qf[2][2];
#pragma unroll
  for (int mi = 0; mi < 2; ++mi)
#pragma unroll
    for (int kk = 0; kk < 2; ++kk) {
      int qrow = q0 + w * 32 + mi * 16 + lo;
      qf[mi][kk] =
          *(const bf16x8*)(qb + ((size_t)(bh * 2048 + qrow) * 64 + kk * 32 + hi * 8) * 2);
    }

  const f32x4 fz = {0.f, 0.f, 0.f, 0.f};
  f32x4 o[2][4];
  float mx[2][4], ls[2][4];
#pragma unroll
  for (int mi = 0; mi < 2; ++mi) {
#pragma unroll
    for (int dj = 0; dj < 4; ++dj) o[mi][dj] = fz;
#pragma unroll
    for (int j = 0; j < 4; ++j) { mx[mi][j] = -3e38f; ls[mi][j] = 0.f; }
  }

  for (int kt = 0; kt < 32; ++kt) {
    // stage K tile rows kj (128B each) and V^T tile rows d
#pragma unroll
    for (int i = 0; i < 2; ++i) {
      int c = i * 256 + t;
      int r = c >> 3, s = c & 7;
      gload_lds16(kb + (size_t)(bh * 2048 + kt * 64 + r) * 128 + ((s ^ (r & 7)) * 16),
                  Ks + (i * 256 + w * 64) * 16);
      gload_lds16(vb + (size_t)(bh * 64 + r) * 4096 + (size_t)kt * 128 + ((s ^ (r & 7)) * 16),
                  Vs + (i * 256 + w * 64) * 16);
    }
    __syncthreads();

    // QK^T : D[qi][kj]
    f32x4 sc[2][4];
#pragma unroll
    for (int mi = 0; mi < 2; ++mi)
#pragma unroll
      for (int ni = 0; ni < 4; ++ni) sc[mi][ni] = fz;
#pragma unroll
    for (int kk = 0; kk < 2; ++kk) {
      bf16x8 kf[4];
#pragma unroll
      for (int ni = 0; ni < 4; ++ni)
        kf[ni] = *(const bf16x8*)(Ks + (ni * 16 + lo) * 128 + ((kk * 64 + hi * 16) ^ (l7 << 4)));
#pragma unroll
      for (int mi = 0; mi < 2; ++mi)
#pragma unroll
        for (int ni = 0; ni < 4; ++ni)
          sc[mi][ni] =
              __builtin_amdgcn_mfma_f32_16x16x32_bf16(qf[mi][kk], kf[ni], sc[mi][ni], 0, 0, 0);
    }

    // masked online softmax; 16 lanes (bit0-3) share each row
#pragma unroll
    for (int mi = 0; mi < 2; ++mi)
#pragma unroll
      for (int j = 0; j < 4; ++j) {
        int qrow = q0 + w * 32 + mi * 16 + hi * 4 + j;
        unsigned long long mw = mbits[(size_t)(b * 2048 + qrow) * 32 + kt];
        float sv[4];
#pragma unroll
        for (int ni = 0; ni < 4; ++ni) {
          int cb = ni * 16 + lo;
          sv[ni] = ((mw >> cb) & 1ull) ? sc[mi][ni][j] : -1e9f;
        }
        float tm = fmaxf(fmaxf(sv[0], sv[1]), fmaxf(sv[2], sv[3]));
#pragma unroll
        for (int off = 1; off < 16; off <<= 1) tm = fmaxf(tm, __shfl_xor(tm, off));
        float mn = fmaxf(mx[mi][j], tm);
        float scal = __expf(mx[mi][j] - mn);
        float ps = 0.f;
        int row = mi * 16 + hi * 4 + j;
#pragma unroll
        for (int ni = 0; ni < 4; ++ni) {
          float p = __expf(sv[ni] - mn);
          ps += p;
          int col = ni * 16 + lo;
          *(bf16*)(Ps + row * 128 + ((col * 2) ^ ((row & 7) << 4))) = (bf16)p;
        }
#pragma unroll
        for (int off = 1; off < 16; off <<= 1) ps += __shfl_xor(ps, off);
        ls[mi][j] = ls[mi][j] * scal + ps;
        mx[mi][j] = mn;
#pragma unroll
        for (int dj = 0; dj < 4; ++dj) o[mi][dj][j] *= scal;
      }

    // PV: o[qi][d] += P[qi][kj] * V[kj][d]
#pragma unroll
    for (int kk = 0; kk < 2; ++kk) {
      bf16x8 pf[2], vf[4];
#pragma unroll
      for (int mi = 0; mi < 2; ++mi)
        pf[mi] = *(const bf16x8*)(Ps + (mi * 16 + lo) * 128 + ((kk * 64 + hi * 16) ^ (l7 << 4)));
#pragma unroll
      for (int dj = 0; dj < 4; ++dj)
        vf[dj] = *(const bf16x8*)(Vs + (dj * 16 + lo) * 128 + ((kk * 64 + hi * 16) ^ (l7 << 4)));
#pragma unroll
      for (int mi = 0; mi < 2; ++mi)
#pragma unroll
        for (int dj = 0; dj < 4; ++dj)
          o[mi][dj] = __builtin_amdgcn_mfma_f32_16x16x32_bf16(pf[mi], vf[dj], o[mi][dj], 0, 0, 0);
    }
    __syncthreads();
  }

  // epilogue: attn[b*2048+qi][h*64+d] bf16
  const int h = bh & 15;
#pragma unroll
  for (int mi = 0; mi < 2; ++mi)
#pragma unroll
    for (int j = 0; j < 4; ++j) {
      float inv = 1.f / ls[mi][j];
      int grow = (b << 11) + q0 + w * 32 + mi * 16 + hi * 4 + j;
#pragma unroll
      for (int dj = 0; dj < 4; ++dj) {
        int gcol = h * 64 + dj * 16 + lo;
        out[(size_t)grow * 1024 + gcol] = (bf16)(o[mi][dj][j] * inv);
      }
    }
}

extern "C" void kernel_launch(void* const* d_in, const int* in_sizes, int n_in,
                              void* d_out, int out_size, void* d_ws, size_t ws_size,
                              hipStream_t stream) {
  const float* query = (const float*)d_in[0];
  const float* key_ = (const float*)d_in[1];
  const float* value = (const float*)d_in[2];
  const int* mask = (const int*)d_in[3];
  const float* Wq = (const float*)d_in[4];
  const float* bq = (const float*)d_in[5];
  const float* Wk = (const float*)d_in[6];
  const float* bk = (const float*)d_in[7];
  const float* Wv = (const float*)d_in[8];
  const float* bv = (const float*)d_in[9];
  const float* Wo = (const float*)d_in[10];
  const float* bo = (const float*)d_in[11];

  char* ws = (char*)d_ws;
  bf16* wt = (bf16*)ws;                      // 4 x 1M bf16
  char* qbuf = ws + 8388608;
  char* kbuf = qbuf + 16777216;
  char* vbuf = kbuf + 16777216;
  char* abuf = vbuf + 16777216;
  unsigned long long* mbits = (unsigned long long*)(abuf + 16777216);

  wt_kernel<<<dim3(16, 16, 4), 256, 0, stream>>>(Wq, Wk, Wv, Wo, wt);
  maskpack_kernel<<<65536, 256, 0, stream>>>(mask, mbits);
  gemm_kernel<0><<<dim3(64, 8), 256, 0, stream>>>(query, wt, bq, qbuf);
  gemm_kernel<1><<<dim3(64, 8), 256, 0, stream>>>(key_, wt + 1048576, bk, kbuf);
  gemm_kernel<2><<<dim3(64, 8), 256, 0, stream>>>(value, wt + 2097152, bv, vbuf);
  attn_kernel<<<dim3(16, 64), 256, 0, stream>>>(qbuf, kbuf, vbuf, mbits, (bf16*)abuf);
  gemm_kernel<3><<<dim3(64, 8), 256, 0, stream>>>(abuf, wt + 3145728, bo, d_out);
}

// Round 3
// 326.527 us; speedup vs baseline: 1.2749x; 1.2749x over previous
//
#include <hip/hip_runtime.h>
#include <hip/hip_bf16.h>

// MHA: B=4, S=2048, D_MODEL=1024, H=16, DK=64
// ws layout (bytes):
//   [0, 8388608)            Wt: 4 x bf16[1024][1024]  (row n, col k)  = W^T
//   [8388608, +16777216)    Q  bf16 [B][H][S][64]
//   next  +16777216         K  bf16 [B][H][S][64]
//   next  +16777216         V  bf16 [B][H][64][S]
//   next  +16777216         attn out bf16 [8192][1024]
//   next  +2097152          mask bits u64 [B][S][S/64]
// total 77,594,624 B

typedef __bf16 bf16;
typedef __bf16 bf16x4 __attribute__((ext_vector_type(4)));
typedef __bf16 bf16x8 __attribute__((ext_vector_type(8)));
typedef float f32x4 __attribute__((ext_vector_type(4)));

__device__ __forceinline__ void gload_lds16(const void* g, void* l) {
  __builtin_amdgcn_global_load_lds(
      (__attribute__((address_space(1))) void*)g,
      (__attribute__((address_space(3))) void*)l, 16, 0, 0);
}

// ---------------- W transpose + bf16 convert ----------------
__global__ __launch_bounds__(256) void wt_kernel(const float* __restrict__ Wq,
                                                 const float* __restrict__ Wk,
                                                 const float* __restrict__ Wv,
                                                 const float* __restrict__ Wo,
                                                 bf16* __restrict__ wt) {
  __shared__ float tile[64][65];
  const int z = blockIdx.z;
  const float* W = (z == 0) ? Wq : (z == 1) ? Wk : (z == 2) ? Wv : Wo;
  bf16* out = wt + (size_t)z * 1048576;
  const int k0 = blockIdx.x * 64, n0 = blockIdx.y * 64;
  for (int e = threadIdx.x; e < 4096; e += 256) {
    int r = e >> 6, c = e & 63;
    tile[r][c] = W[(size_t)(k0 + r) * 1024 + n0 + c];
  }
  __syncthreads();
  for (int e = threadIdx.x; e < 4096; e += 256) {
    int r = e >> 6, c = e & 63;
    out[(size_t)(n0 + r) * 1024 + k0 + c] = (bf16)tile[c][r];
  }
}

// ---------------- mask -> bit pack ----------------
__global__ __launch_bounds__(256) void maskpack_kernel(const int* __restrict__ mask,
                                                       unsigned long long* __restrict__ bits) {
  const int gid = blockIdx.x * 256 + threadIdx.x;
  const int word = gid >> 6;
  const int lane = threadIdx.x & 63;
  int v = mask[(size_t)word * 64 + lane];
  unsigned long long b = __ballot(v != 0);
  if (lane == 0) bits[word] = b;
}

// ---------------- GEMM: C[8192][1024] = A[8192][1024] @ Bt^T + bias ----------------
// MODE 0: A fp32, out Q bf16 [B][H][S][64], (acc+bias)*0.125
// MODE 1: A fp32, out K bf16 [B][H][S][64]
// MODE 2: A fp32, out V bf16 [B][H][64][S]
// MODE 3: A bf16, out fp32 row-major [8192][1024]
template <int MODE>
__global__ __launch_bounds__(256) void gemm_kernel(const void* __restrict__ Aptr,
                                                   const bf16* __restrict__ Bt,
                                                   const float* __restrict__ bias,
                                                   void* __restrict__ Out) {
  __shared__ alignas(16) char smem[32768];
  char* As = smem;            // [128][64] bf16, 16B-slot XOR swizzle by row&7
  char* Bs = smem + 16384;    // [128 n][64 k] bf16, same swizzle
  const int t = threadIdx.x;
  const int w = t >> 6, l = t & 63;
  const int hi = l >> 4, lo = l & 15, l7 = l & 7;
  const int wr = w >> 1, wc = w & 1;
  const int row0 = blockIdx.x * 128;
  const int n0 = blockIdx.y * 128;

  const f32x4 fz = {0.f, 0.f, 0.f, 0.f};
  f32x4 acc[4][4];
#pragma unroll
  for (int mi = 0; mi < 4; ++mi)
#pragma unroll
    for (int ni = 0; ni < 4; ++ni) acc[mi][ni] = fz;

  for (int kt = 0; kt < 16; ++kt) {
    if constexpr (MODE < 3) {
      const float* A = (const float*)Aptr;
#pragma unroll
      for (int i = 0; i < 8; ++i) {
        int qq = i * 256 + t;
        int r = qq >> 4, q = qq & 15;  // row, 4-float quad along k
        f32x4 f = *(const f32x4*)(A + (size_t)(row0 + r) * 1024 + kt * 64 + q * 4);
        bf16x4 h = {(bf16)f[0], (bf16)f[1], (bf16)f[2], (bf16)f[3]};
        *(bf16x4*)(As + r * 128 + ((q * 8) ^ ((r & 7) << 4))) = h;
      }
    } else {
      const char* A = (const char*)Aptr;  // bf16 [8192][1024]
#pragma unroll
      for (int i = 0; i < 4; ++i) {
        int c = i * 256 + t;
        int r = c >> 3, s = c & 7;
        gload_lds16(A + (size_t)(row0 + r) * 2048 + kt * 128 + ((s ^ (r & 7)) * 16),
                    As + (i * 256 + w * 64) * 16);
      }
    }
    {
      const char* Bb = (const char*)Bt;  // bf16 [1024 n][1024 k]
#pragma unroll
      for (int i = 0; i < 4; ++i) {
        int c = i * 256 + t;
        int r = c >> 3, s = c & 7;
        gload_lds16(Bb + (size_t)(n0 + r) * 2048 + kt * 128 + ((s ^ (r & 7)) * 16),
                    Bs + (i * 256 + w * 64) * 16);
      }
    }
    __syncthreads();
#pragma unroll
    for (int kk = 0; kk < 2; ++kk) {
      bf16x8 af[4], bfr[4];
#pragma unroll
      for (int mi = 0; mi < 4; ++mi)
        af[mi] = *(const bf16x8*)(As + (wr * 64 + mi * 16 + lo) * 128 +
                                  ((kk * 64 + hi * 16) ^ (l7 << 4)));
#pragma unroll
      for (int ni = 0; ni < 4; ++ni)
        bfr[ni] = *(const bf16x8*)(Bs + (wc * 64 + ni * 16 + lo) * 128 +
                                   ((kk * 64 + hi * 16) ^ (l7 << 4)));
#pragma unroll
      for (int mi = 0; mi < 4; ++mi)
#pragma unroll
        for (int ni = 0; ni < 4; ++ni)
          acc[mi][ni] =
              __builtin_amdgcn_mfma_f32_16x16x32_bf16(af[mi], bfr[ni], acc[mi][ni], 0, 0, 0);
    }
    __syncthreads();
  }

  // epilogue: D row=(lane>>4)*4+j, col=lane&15 (m89-verified)
#pragma unroll
  for (int mi = 0; mi < 4; ++mi)
#pragma unroll
    for (int ni = 0; ni < 4; ++ni) {
      int gcol = n0 + wc * 64 + ni * 16 + lo;
      float bv = bias[gcol];
#pragma unroll
      for (int j = 0; j < 4; ++j) {
        int grow = row0 + wr * 64 + mi * 16 + hi * 4 + j;
        float v = acc[mi][ni][j] + bv;
        if constexpr (MODE == 0) v *= 0.125f;  // fold 1/sqrt(DK) into Q
        if constexpr (MODE <= 1) {
          int b = grow >> 11, si = grow & 2047, h = gcol >> 6, d = gcol & 63;
          ((bf16*)Out)[((((size_t)b * 16 + h) * 2048 + si) << 6) + d] = (bf16)v;
        } else if constexpr (MODE == 2) {
          int b = grow >> 11, si = grow & 2047, h = gcol >> 6, d = gcol & 63;
          ((bf16*)Out)[((((size_t)b * 16 + h) * 64 + d) << 11) + si] = (bf16)v;
        } else {
          ((float*)Out)[(size_t)grow * 1024 + gcol] = v;
        }
      }
    }
}

// ---------------- flash attention (transposed-score layout, 2-barrier schedule) ----------------
// grid (B*H=64, S/128=16), 256 thr. Same-head blocks share XCD (id = y*64+x -> x%8).
// wave w owns q rows [q0+32w, q0+32w+32).
// Per outer step: stage K[128 kj][64 d] (16KB) + V[64 d][128 kj] (16KB), barrier,
// compute two 64-kj halves, barrier.  (proven round-1 sync pattern, fewer barriers)
// QK^T swapped: sc = mfma(K, Q) -> sc[kj][qi], qi = lane&15 (lane-local q-row).
// PV transposed: o = mfma(V^T, P) -> O^T[d][qi] -> lane-uniform rescale.
__global__ __launch_bounds__(256) void attn_kernel(const char* __restrict__ qb,
                                                   const char* __restrict__ kb,
                                                   const char* __restrict__ vb,
                                                   const unsigned long long* __restrict__ mbits,
                                                   bf16* __restrict__ out) {
  __shared__ alignas(16) char smem[49152];
  // [0,16384): Ks [128 kj][64 d] swizzled; [16384,32768): Vs [64 d][128 kj] swizzled
  const int t = threadIdx.x;
  const int w = t >> 6, l = t & 63;
  const int hi = l >> 4, lo = l & 15, l7 = l & 7;
  char* Ps = smem + 32768 + w * 4096;  // per-wave P [32 qi][64 kj] bf16, swizzled
  const int bh = blockIdx.x, b = bh >> 4, h = bh & 15;
  const int q0 = blockIdx.y * 128;
  const int qrow = q0 + w * 32 + lo;  // this lane's q-rows: qrow + mi*16

  // Q fragments (B-operand): row qi = mi*16+lo, k-chunk hi*8 (scaled by 0.125 already)
  bf16x8 qf[2][2];
#pragma unroll
  for (int mi = 0; mi < 2; ++mi)
#pragma unroll
    for (int kk = 0; kk < 2; ++kk)
      qf[mi][kk] = *(const bf16x8*)(qb + ((size_t)(bh * 2048 + qrow + mi * 16) * 64 +
                                          kk * 32 + hi * 8) * 2);

  const f32x4 fz = {0.f, 0.f, 0.f, 0.f};
  f32x4 o[4][2];  // [dj][mi]: O^T[d = dj*16+hi*4+reg][qi = mi*16+lo]
  float mx[2] = {-3e38f, -3e38f}, ls[2] = {0.f, 0.f};
#pragma unroll
  for (int dj = 0; dj < 4; ++dj)
#pragma unroll
    for (int mi = 0; mi < 2; ++mi) o[dj][mi] = fz;

  for (int kt2 = 0; kt2 < 16; ++kt2) {
    // stage K tile (128 rows x 8 slots) and V tile (64 rows x 16 slots)
#pragma unroll
    for (int i = 0; i < 4; ++i) {
      int c = i * 256 + t;
      int kr = c >> 3, ks = c & 7;
      gload_lds16(kb + (size_t)(bh * 2048 + kt2 * 128 + kr) * 128 + ((ks ^ (kr & 7)) * 16),
                  smem + (i * 256 + w * 64) * 16);
      int vr = c >> 4, vs = c & 15;
      gload_lds16(vb + (size_t)(bh * 64 + vr) * 4096 + kt2 * 256 + ((vs ^ (vr & 7)) * 16),
                  smem + 16384 + (i * 256 + w * 64) * 16);
    }
    __syncthreads();

#pragma unroll
    for (int h2 = 0; h2 < 2; ++h2) {
      const char* Kb = smem + h2 * 8192;  // rows [h2*64, h2*64+64) of the K tile
      const char* Vb = smem + 16384;      // byte-in-row offset carries h2*128
      const int kt = kt2 * 2 + h2;

      unsigned long long mw[2];
#pragma unroll
      for (int mi = 0; mi < 2; ++mi)
        mw[mi] = mbits[(size_t)(b * 2048 + qrow + mi * 16) * 32 + kt];

      // QK^T swapped: sc[ni][mi] = D[kj = ni*16+hi*4+reg][qi = mi*16+lo]
      f32x4 sc[4][2];
#pragma unroll
      for (int ni = 0; ni < 4; ++ni)
#pragma unroll
        for (int mi = 0; mi < 2; ++mi) sc[ni][mi] = fz;
#pragma unroll
      for (int kk = 0; kk < 2; ++kk) {
        bf16x8 kf[4];
#pragma unroll
        for (int ni = 0; ni < 4; ++ni)
          kf[ni] =
              *(const bf16x8*)(Kb + (ni * 16 + lo) * 128 + ((kk * 64 + hi * 16) ^ (l7 << 4)));
#pragma unroll
        for (int ni = 0; ni < 4; ++ni)
#pragma unroll
          for (int mi = 0; mi < 2; ++mi)
            sc[ni][mi] =
                __builtin_amdgcn_mfma_f32_16x16x32_bf16(kf[ni], qf[mi][kk], sc[ni][mi], 0, 0, 0);
      }

      // online softmax: q-row is lane-local (qi = lo); 4 hi-lanes split the 64 kj
#pragma unroll
      for (int mi = 0; mi < 2; ++mi) {
        float sv[4][4];
#pragma unroll
        for (int ni = 0; ni < 4; ++ni)
#pragma unroll
          for (int j = 0; j < 4; ++j)
            sv[ni][j] = ((mw[mi] >> (ni * 16 + hi * 4 + j)) & 1ull) ? sc[ni][mi][j] : -1e9f;
        float tm = sv[0][0];
#pragma unroll
        for (int ni = 0; ni < 4; ++ni)
#pragma unroll
          for (int j = 0; j < 4; ++j) tm = fmaxf(tm, sv[ni][j]);
        tm = fmaxf(tm, __shfl_xor(tm, 16));
        tm = fmaxf(tm, __shfl_xor(tm, 32));
        float mn = fmaxf(mx[mi], tm);
        float scal = __expf(mx[mi] - mn);
        float ps = 0.f;
        const int row = mi * 16 + lo;
#pragma unroll
        for (int ni = 0; ni < 4; ++ni) {
          float p0 = __expf(sv[ni][0] - mn), p1 = __expf(sv[ni][1] - mn);
          float p2 = __expf(sv[ni][2] - mn), p3 = __expf(sv[ni][3] - mn);
          ps += (p0 + p1) + (p2 + p3);
          bf16x4 hq = {(bf16)p0, (bf16)p1, (bf16)p2, (bf16)p3};
          *(bf16x4*)(Ps + row * 128 + ((ni * 32 + hi * 8) ^ ((row & 7) << 4))) = hq;
        }
        ps += __shfl_xor(ps, 16);
        ps += __shfl_xor(ps, 32);
        ls[mi] = ls[mi] * scal + ps;
        mx[mi] = mn;
#pragma unroll
        for (int dj = 0; dj < 4; ++dj) o[dj][mi] *= scal;
      }

      // PV transposed: o[dj][mi] += mfma(V^T row d, P row qi)
#pragma unroll
      for (int kk = 0; kk < 2; ++kk) {
        bf16x8 pf[2], vf[4];
#pragma unroll
        for (int mi = 0; mi < 2; ++mi)
          pf[mi] =
              *(const bf16x8*)(Ps + (mi * 16 + lo) * 128 + ((kk * 64 + hi * 16) ^ (l7 << 4)));
#pragma unroll
        for (int dj = 0; dj < 4; ++dj)
          vf[dj] = *(const bf16x8*)(Vb + (dj * 16 + lo) * 256 +
                                    ((h2 * 128 + kk * 64 + hi * 16) ^ (l7 << 4)));
#pragma unroll
        for (int dj = 0; dj < 4; ++dj)
#pragma unroll
          for (int mi = 0; mi < 2; ++mi)
            o[dj][mi] =
                __builtin_amdgcn_mfma_f32_16x16x32_bf16(vf[dj], pf[mi], o[dj][mi], 0, 0, 0);
      }
    }
    __syncthreads();
  }

  // epilogue: O^T[d][qi] -> out[b*2048+qi][h*64+d], 4 consecutive d per store
#pragma unroll
  for (int mi = 0; mi < 2; ++mi) {
    float inv = 1.f / ls[mi];
    size_t rbase = (size_t)((b << 11) + qrow + mi * 16) * 1024 + h * 64;
#pragma unroll
    for (int dj = 0; dj < 4; ++dj) {
      bf16x4 hv = {(bf16)(o[dj][mi][0] * inv), (bf16)(o[dj][mi][1] * inv),
                   (bf16)(o[dj][mi][2] * inv), (bf16)(o[dj][mi][3] * inv)};
      *(bf16x4*)(out + rbase + dj * 16 + hi * 4) = hv;
    }
  }
}

extern "C" void kernel_launch(void* const* d_in, const int* in_sizes, int n_in,
                              void* d_out, int out_size, void* d_ws, size_t ws_size,
                              hipStream_t stream) {
  const float* query = (const float*)d_in[0];
  const float* key_ = (const float*)d_in[1];
  const float* value = (const float*)d_in[2];
  const int* mask = (const int*)d_in[3];
  const float* Wq = (const float*)d_in[4];
  const float* bq = (const float*)d_in[5];
  const float* Wk = (const float*)d_in[6];
  const float* bk = (const float*)d_in[7];
  const float* Wv = (const float*)d_in[8];
  const float* bv = (const float*)d_in[9];
  const float* Wo = (const float*)d_in[10];
  const float* bo = (const float*)d_in[11];

  char* ws = (char*)d_ws;
  bf16* wt = (bf16*)ws;                      // 4 x 1M bf16
  char* qbuf = ws + 8388608;
  char* kbuf = qbuf + 16777216;
  char* vbuf = kbuf + 16777216;
  char* abuf = vbuf + 16777216;
  unsigned long long* mbits = (unsigned long long*)(abuf + 16777216);

  wt_kernel<<<dim3(16, 16, 4), 256, 0, stream>>>(Wq, Wk, Wv, Wo, wt);
  maskpack_kernel<<<65536, 256, 0, stream>>>(mask, mbits);
  gemm_kernel<0><<<dim3(64, 8), 256, 0, stream>>>(query, wt, bq, qbuf);
  gemm_kernel<1><<<dim3(64, 8), 256, 0, stream>>>(key_, wt + 1048576, bk, kbuf);
  gemm_kernel<2><<<dim3(64, 8), 256, 0, stream>>>(value, wt + 2097152, bv, vbuf);
  attn_kernel<<<dim3(64, 16), 256, 0, stream>>>(qbuf, kbuf, vbuf, mbits, (bf16*)abuf);
  gemm_kernel<3><<<dim3(64, 8), 256, 0, stream>>>(abuf, wt + 3145728, bo, d_out);
}

// Round 4
// 296.141 us; speedup vs baseline: 1.4057x; 1.1026x over previous
//
#include <hip/hip_runtime.h>
#include <hip/hip_bf16.h>

// MHA: B=4, S=2048, D_MODEL=1024, H=16, DK=64
// ws layout (bytes):
//   [0, 8388608)            Wt: 4 x bf16[1024][1024]  (row n, col k)  = W^T
//   [8388608, +16777216)    Q  bf16 [B][H][S][64]   (scaled by log2e/8)
//   next  +16777216         K  bf16 [B][H][S][64]
//   next  +16777216         V  bf16 [B][H][64][S]
//   next  +16777216         attn out bf16 [8192][1024]
//   next  +2097152          mask bits u64 [B][S][S/64]
// total 77,594,624 B

typedef __bf16 bf16;
typedef __bf16 bf16x4 __attribute__((ext_vector_type(4)));
typedef __bf16 bf16x8 __attribute__((ext_vector_type(8)));
typedef float f32x4 __attribute__((ext_vector_type(4)));
typedef float f32x16 __attribute__((ext_vector_type(16)));
typedef unsigned int uint;

__device__ __forceinline__ void gload_lds16(const void* g, void* l) {
  __builtin_amdgcn_global_load_lds(
      (__attribute__((address_space(1))) void*)g,
      (__attribute__((address_space(3))) void*)l, 16, 0, 0);
}

// ---------------- W transpose + bf16 convert ----------------
__global__ __launch_bounds__(256) void wt_kernel(const float* __restrict__ Wq,
                                                 const float* __restrict__ Wk,
                                                 const float* __restrict__ Wv,
                                                 const float* __restrict__ Wo,
                                                 bf16* __restrict__ wt) {
  __shared__ float tile[64][65];
  const int z = blockIdx.z;
  const float* W = (z == 0) ? Wq : (z == 1) ? Wk : (z == 2) ? Wv : Wo;
  bf16* out = wt + (size_t)z * 1048576;
  const int k0 = blockIdx.x * 64, n0 = blockIdx.y * 64;
  for (int e = threadIdx.x; e < 4096; e += 256) {
    int r = e >> 6, c = e & 63;
    tile[r][c] = W[(size_t)(k0 + r) * 1024 + n0 + c];
  }
  __syncthreads();
  for (int e = threadIdx.x; e < 4096; e += 256) {
    int r = e >> 6, c = e & 63;
    out[(size_t)(n0 + r) * 1024 + k0 + c] = (bf16)tile[c][r];
  }
}

// ---------------- mask -> bit pack ----------------
__global__ __launch_bounds__(256) void maskpack_kernel(const int* __restrict__ mask,
                                                       unsigned long long* __restrict__ bits) {
  const int gid = blockIdx.x * 256 + threadIdx.x;
  const int word = gid >> 6;
  const int lane = threadIdx.x & 63;
  int v = mask[(size_t)word * 64 + lane];
  unsigned long long b = __ballot(v != 0);
  if (lane == 0) bits[word] = b;
}

// ---------------- GEMM: C[8192][1024] = A[8192][1024] @ Bt^T + bias ----------------
// MODE 0: A fp32, out Q bf16 [B][H][S][64], (acc+bias)*(log2e/8)
// MODE 1: A fp32, out K bf16 [B][H][S][64]
// MODE 2: A fp32, out V bf16 [B][H][64][S]
// MODE 3: A bf16, out fp32 row-major [8192][1024]
template <int MODE>
__global__ __launch_bounds__(256) void gemm_kernel(const void* __restrict__ Aptr,
                                                   const bf16* __restrict__ Bt,
                                                   const float* __restrict__ bias,
                                                   void* __restrict__ Out) {
  __shared__ alignas(16) char smem[32768];
  char* As = smem;            // [128][64] bf16, 16B-slot XOR swizzle by row&7
  char* Bs = smem + 16384;    // [128 n][64 k] bf16, same swizzle
  const int t = threadIdx.x;
  const int w = t >> 6, l = t & 63;
  const int hi = l >> 4, lo = l & 15, l7 = l & 7;
  const int wr = w >> 1, wc = w & 1;
  const int row0 = blockIdx.x * 128;
  const int n0 = blockIdx.y * 128;

  const f32x4 fz = {0.f, 0.f, 0.f, 0.f};
  f32x4 acc[4][4];
#pragma unroll
  for (int mi = 0; mi < 4; ++mi)
#pragma unroll
    for (int ni = 0; ni < 4; ++ni) acc[mi][ni] = fz;

  for (int kt = 0; kt < 16; ++kt) {
    if constexpr (MODE < 3) {
      const float* A = (const float*)Aptr;
#pragma unroll
      for (int i = 0; i < 8; ++i) {
        int qq = i * 256 + t;
        int r = qq >> 4, q = qq & 15;  // row, 4-float quad along k
        f32x4 f = *(const f32x4*)(A + (size_t)(row0 + r) * 1024 + kt * 64 + q * 4);
        bf16x4 h = {(bf16)f[0], (bf16)f[1], (bf16)f[2], (bf16)f[3]};
        *(bf16x4*)(As + r * 128 + ((q * 8) ^ ((r & 7) << 4))) = h;
      }
    } else {
      const char* A = (const char*)Aptr;  // bf16 [8192][1024]
#pragma unroll
      for (int i = 0; i < 4; ++i) {
        int c = i * 256 + t;
        int r = c >> 3, s = c & 7;
        gload_lds16(A + (size_t)(row0 + r) * 2048 + kt * 128 + ((s ^ (r & 7)) * 16),
                    As + (i * 256 + w * 64) * 16);
      }
    }
    {
      const char* Bb = (const char*)Bt;  // bf16 [1024 n][1024 k]
#pragma unroll
      for (int i = 0; i < 4; ++i) {
        int c = i * 256 + t;
        int r = c >> 3, s = c & 7;
        gload_lds16(Bb + (size_t)(n0 + r) * 2048 + kt * 128 + ((s ^ (r & 7)) * 16),
                    Bs + (i * 256 + w * 64) * 16);
      }
    }
    __syncthreads();
#pragma unroll
    for (int kk = 0; kk < 2; ++kk) {
      bf16x8 af[4], bfr[4];
#pragma unroll
      for (int mi = 0; mi < 4; ++mi)
        af[mi] = *(const bf16x8*)(As + (wr * 64 + mi * 16 + lo) * 128 +
                                  ((kk * 64 + hi * 16) ^ (l7 << 4)));
#pragma unroll
      for (int ni = 0; ni < 4; ++ni)
        bfr[ni] = *(const bf16x8*)(Bs + (wc * 64 + ni * 16 + lo) * 128 +
                                   ((kk * 64 + hi * 16) ^ (l7 << 4)));
#pragma unroll
      for (int mi = 0; mi < 4; ++mi)
#pragma unroll
        for (int ni = 0; ni < 4; ++ni)
          acc[mi][ni] =
              __builtin_amdgcn_mfma_f32_16x16x32_bf16(af[mi], bfr[ni], acc[mi][ni], 0, 0, 0);
    }
    __syncthreads();
  }

  // epilogue: D row=(lane>>4)*4+j, col=lane&15 (m89-verified)
#pragma unroll
  for (int mi = 0; mi < 4; ++mi)
#pragma unroll
    for (int ni = 0; ni < 4; ++ni) {
      int gcol = n0 + wc * 64 + ni * 16 + lo;
      float bv = bias[gcol];
#pragma unroll
      for (int j = 0; j < 4; ++j) {
        int grow = row0 + wr * 64 + mi * 16 + hi * 4 + j;
        float v = acc[mi][ni][j] + bv;
        if constexpr (MODE == 0) v *= 0.18033688011112042f;  // (1/8)*log2(e): exp2 domain
        if constexpr (MODE <= 1) {
          int b = grow >> 11, si = grow & 2047, h = gcol >> 6, d = gcol & 63;
          ((bf16*)Out)[((((size_t)b * 16 + h) * 2048 + si) << 6) + d] = (bf16)v;
        } else if constexpr (MODE == 2) {
          int b = grow >> 11, si = grow & 2047, h = gcol >> 6, d = gcol & 63;
          ((bf16*)Out)[((((size_t)b * 16 + h) * 64 + d) << 11) + si] = (bf16)v;
        } else {
          ((float*)Out)[(size_t)grow * 1024 + gcol] = v;
        }
      }
    }
}

// ---------------- flash attention (32x32 MFMA, in-register softmax) ----------------
// grid (B*H=64, S/128=16), 256 thr. Same-head blocks share XCD (id = y*64+x -> x%8).
// wave w owns 32 q rows; lane owns q-row qi = lane&31 (lanes l, l^32 share a row,
// hi = l>>5 splits the kj/d axis).
// QK^T swapped: sc[n] = mfma32x32x16(K, Q) -> D[kj][qi], kj = n*32+(r&3)+8*(r>>2)+4*hi.
// Softmax in-register (1 shfl per tile). P -> bf16 via v_cvt_pk_bf16_f32, fragments
// built with v_permlane32_swap_b32 (T12). PV: o[db] = mfma(V^T, P) -> O^T[d][qi].
__global__ __launch_bounds__(256) void attn_kernel(const char* __restrict__ qb,
                                                   const char* __restrict__ kb,
                                                   const char* __restrict__ vb,
                                                   const unsigned long long* __restrict__ mbits,
                                                   bf16* __restrict__ out) {
  __shared__ alignas(16) char smem[32768];
  // [0,16384): Ks [128 kj][8 slots x16B], slot ^= row&7
  // [16384,32768): Vs [64 d][16 slots x16B], slot ^= row&7
  const int t = threadIdx.x;
  const int w = t >> 6, l = t & 63;
  const int q31 = l & 31, hi = l >> 5;
  const int bh = blockIdx.x, b = bh >> 4, h = bh & 15;
  const int q0 = blockIdx.y * 128;
  const int qrow = q0 + w * 32 + q31;

  // Q fragments (B-operand of 32x32x16): col=qi=q31, k = kc*16 + hi*8 + e
  bf16x8 qf[4];
#pragma unroll
  for (int kc = 0; kc < 4; ++kc)
    qf[kc] = *(const bf16x8*)(qb + (size_t)(bh * 2048 + qrow) * 128 + kc * 32 + hi * 16);

  const f32x16 fz16 = {0.f, 0.f, 0.f, 0.f, 0.f, 0.f, 0.f, 0.f,
                       0.f, 0.f, 0.f, 0.f, 0.f, 0.f, 0.f, 0.f};
  f32x16 o[2];  // o[db]: O^T[d = db*32+(r&3)+8*(r>>2)+4*hi][qi=q31]
  o[0] = fz16;
  o[1] = fz16;
  float mreg = -3e38f, ls = 0.f;
  const unsigned long long* mrow = mbits + (size_t)(b * 2048 + qrow) * 32;

  for (int kt2 = 0; kt2 < 16; ++kt2) {
    // stage K[128 kj][64 d] and V^T[64 d][128 kj] (16KB each), swizzled
#pragma unroll
    for (int i = 0; i < 4; ++i) {
      int c = i * 256 + t;
      int kr = c >> 3, ks = c & 7;
      gload_lds16(kb + (size_t)(bh * 2048 + kt2 * 128 + kr) * 128 + ((ks ^ (kr & 7)) * 16),
                  smem + (i * 256 + w * 64) * 16);
      int vr = c >> 4, vs = c & 15;
      gload_lds16(vb + (size_t)(bh * 64 + vr) * 4096 + kt2 * 256 + ((vs ^ (vr & 7)) * 16),
                  smem + 16384 + (i * 256 + w * 64) * 16);
    }
    __syncthreads();

#pragma unroll
    for (int h2 = 0; h2 < 2; ++h2) {
      const int kt = kt2 * 2 + h2;
      const unsigned long long mw = mrow[kt];

      // QK^T: sc[n] = D[kj = n*32 + crow(r,hi)][qi]
      f32x16 sc[2];
      sc[0] = fz16;
      sc[1] = fz16;
      __builtin_amdgcn_s_setprio(1);
#pragma unroll
      for (int kc = 0; kc < 4; ++kc) {
        bf16x8 kf0 = *(const bf16x8*)(smem + (h2 * 64 + q31) * 128 +
                                      (((kc * 2 + hi) ^ (q31 & 7)) * 16));
        bf16x8 kf1 = *(const bf16x8*)(smem + (h2 * 64 + 32 + q31) * 128 +
                                      (((kc * 2 + hi) ^ (q31 & 7)) * 16));
        sc[0] = __builtin_amdgcn_mfma_f32_32x32x16_bf16(kf0, qf[kc], sc[0], 0, 0, 0);
        sc[1] = __builtin_amdgcn_mfma_f32_32x32x16_bf16(kf1, qf[kc], sc[1], 0, 0, 0);
      }
      __builtin_amdgcn_s_setprio(0);

      // mask + row max (scores already in log2 domain)
      float sv[2][16];
      float tm = -3e38f;
#pragma unroll
      for (int n = 0; n < 2; ++n) {
        uint m32 = (uint)(mw >> (n * 32 + 4 * hi));
#pragma unroll
        for (int r = 0; r < 16; ++r) {
          const int bi = (r & 3) + 8 * (r >> 2);
          float x = ((m32 >> bi) & 1u) ? sc[n][r] : -1e9f;
          sv[n][r] = x;
          tm = fmaxf(tm, x);
        }
      }
      tm = fmaxf(tm, __shfl_xor(tm, 32));

      // defer-max (T13, THR=4): rescale only when tile max grows past mreg+4
      if (!__all(tm - mreg <= 4.f)) {
        float mn = fmaxf(mreg, tm);
        float scal = __builtin_amdgcn_exp2f(mreg - mn);
        ls *= scal;
        o[0] *= scal;
        o[1] *= scal;
        mreg = mn;
      }

      // p = exp2(sv - mreg); pack pairs to bf16x2 words
      uint wpk[2][8];
#pragma unroll
      for (int n = 0; n < 2; ++n)
#pragma unroll
        for (int r2 = 0; r2 < 8; ++r2) {
          float p0 = __builtin_amdgcn_exp2f(sv[n][2 * r2] - mreg);
          float p1 = __builtin_amdgcn_exp2f(sv[n][2 * r2 + 1] - mreg);
          ls += p0 + p1;
          uint pk;
          asm("v_cvt_pk_bf16_f32 %0, %1, %2" : "=v"(pk) : "v"(p0), "v"(p1));
          wpk[n][r2] = pk;
        }

      // build P fragments via permlane32_swap and run PV
      __builtin_amdgcn_s_setprio(1);
#pragma unroll
      for (int n = 0; n < 2; ++n)
#pragma unroll
        for (int c2 = 0; c2 < 2; ++c2) {
          uint a0 = wpk[n][4 * c2], b0 = wpk[n][4 * c2 + 2];
          uint a1 = wpk[n][4 * c2 + 1], b1 = wpk[n][4 * c2 + 3];
          asm("v_permlane32_swap_b32 %0, %1" : "+v"(a0), "+v"(b0));
          asm("v_permlane32_swap_b32 %0, %1" : "+v"(a1), "+v"(b1));
          union {
            uint u[4];
            bf16x8 v;
          } pf;
          pf.u[0] = a0;
          pf.u[1] = a1;
          pf.u[2] = b0;
          pf.u[3] = b1;
          const int c = n * 2 + c2;  // kj chunk: kj = c*16 + hi*8 + e
          const int slot = (h2 * 8 + c * 2 + hi);
          bf16x8 vf0 = *(const bf16x8*)(smem + 16384 + q31 * 256 +
                                        ((slot ^ (q31 & 7)) * 16));
          bf16x8 vf1 = *(const bf16x8*)(smem + 16384 + (32 + q31) * 256 +
                                        ((slot ^ (q31 & 7)) * 16));
          o[0] = __builtin_amdgcn_mfma_f32_32x32x16_bf16(vf0, pf.v, o[0], 0, 0, 0);
          o[1] = __builtin_amdgcn_mfma_f32_32x32x16_bf16(vf1, pf.v, o[1], 0, 0, 0);
        }
      __builtin_amdgcn_s_setprio(0);
    }
    __syncthreads();
  }

  // epilogue: both hi-halves hold partial ls; combine once
  ls += __shfl_xor(ls, 32);
  float inv = 1.f / ls;
  size_t rbase = (size_t)((b << 11) + qrow) * 1024 + h * 64;
#pragma unroll
  for (int db = 0; db < 2; ++db)
#pragma unroll
    for (int g = 0; g < 4; ++g) {
      bf16x4 hv = {(bf16)(o[db][4 * g] * inv), (bf16)(o[db][4 * g + 1] * inv),
                   (bf16)(o[db][4 * g + 2] * inv), (bf16)(o[db][4 * g + 3] * inv)};
      *(bf16x4*)(out + rbase + db * 32 + 8 * g + 4 * hi) = hv;
    }
}

extern "C" void kernel_launch(void* const* d_in, const int* in_sizes, int n_in,
                              void* d_out, int out_size, void* d_ws, size_t ws_size,
                              hipStream_t stream) {
  const float* query = (const float*)d_in[0];
  const float* key_ = (const float*)d_in[1];
  const float* value = (const float*)d_in[2];
  const int* mask = (const int*)d_in[3];
  const float* Wq = (const float*)d_in[4];
  const float* bq = (const float*)d_in[5];
  const float* Wk = (const float*)d_in[6];
  const float* bk = (const float*)d_in[7];
  const float* Wv = (const float*)d_in[8];
  const float* bv = (const float*)d_in[9];
  const float* Wo = (const float*)d_in[10];
  const float* bo = (const float*)d_in[11];

  char* ws = (char*)d_ws;
  bf16* wt = (bf16*)ws;                      // 4 x 1M bf16
  char* qbuf = ws + 8388608;
  char* kbuf = qbuf + 16777216;
  char* vbuf = kbuf + 16777216;
  char* abuf = vbuf + 16777216;
  unsigned long long* mbits = (unsigned long long*)(abuf + 16777216);

  wt_kernel<<<dim3(16, 16, 4), 256, 0, stream>>>(Wq, Wk, Wv, Wo, wt);
  maskpack_kernel<<<65536, 256, 0, stream>>>(mask, mbits);
  gemm_kernel<0><<<dim3(64, 8), 256, 0, stream>>>(query, wt, bq, qbuf);
  gemm_kernel<1><<<dim3(64, 8), 256, 0, stream>>>(key_, wt + 1048576, bk, kbuf);
  gemm_kernel<2><<<dim3(64, 8), 256, 0, stream>>>(value, wt + 2097152, bv, vbuf);
  attn_kernel<<<dim3(64, 16), 256, 0, stream>>>(qbuf, kbuf, vbuf, mbits, (bf16*)abuf);
  gemm_kernel<3><<<dim3(64, 8), 256, 0, stream>>>(abuf, wt + 3145728, bo, d_out);
}